// Round 1
// 160.235 us; speedup vs baseline: 1.0506x; 1.0506x over previous
//
#include <hip/hip_runtime.h>
#include <math.h>

#define N 4096
#define B 16
#define NN (N * N)
#define R 4                    // rows per block == waves per block
#define MAX_SYN 100
#define MIN_SYN 10
#define CREATE_T 0.3f
#define PRUNE_T 0.01f
#define INIT_STRENGTH 0.01f
#define EPS 1e-10f
#define BF_BASE 0x3E9Au        // bf16 code of smallest candidate magnitude (>0.3 rounds to >= 0x3E9A)
#define CAPC 1536              // per-row candidate list cap (~900 expected, 25 sigma margin)
#define CAPM 64                // boundary (tie) list cap
#define CAPS 32                // small-weight (EPS<|w|<PRUNE_T) list cap
#define NSLOT 64

typedef float f32x4 __attribute__((ext_vector_type(4)));

// ---------------- kernel 1: per-column normalization + acc zeroing ----------------
__global__ void prep_kernel(const float* __restrict__ act,
                            float* __restrict__ norm,
                            float* __restrict__ acc) {
    int j = blockIdx.x * blockDim.x + threadIdx.x;
    if (blockIdx.x == 0 && threadIdx.x < NSLOT * 4) acc[threadIdx.x] = 0.f;
    if (j >= N) return;
    float a[B];
    float sum = 0.f;
#pragma unroll
    for (int b = 0; b < B; ++b) { a[b] = act[b * N + j]; sum += a[b]; }
    float mean = sum * (1.0f / B);
    float var = 0.f;
#pragma unroll
    for (int b = 0; b < B; ++b) { float c = a[b] - mean; var += c * c; }
    var *= (1.0f / (B - 1));   // ddof=1
    float sd = sqrtf(var);
    if (sd < 1e-8f) sd = 1e-8f;
    float inv = 1.0f / sd;
#pragma unroll
    for (int b = 0; b < B; ++b) norm[b * N + j] = (a[b] - mean) * inv;
}

// ---------------- kernel 2: single-pass stream + list-based selection ----------------
__global__ __launch_bounds__(256, 4) void fused_kernel(const float* __restrict__ W,
                                                       const float* __restrict__ norm,
                                                       float* __restrict__ out,
                                                       float* __restrict__ acc) {
    __shared__ unsigned cand[R][CAPC];       // (bf16mag<<16)|(sign<<15)|col
    __shared__ int hist[R][256];
    __shared__ unsigned mlist[R][CAPM];
    __shared__ unsigned short slist[R][CAPS];
    __shared__ int ccnt[R];
    __shared__ int mcnt[R];
    __shared__ int scnt[R];
    __shared__ int red[4][8];

    const int tid = threadIdx.x;
    const int lane = tid & 63;
    const int wid = tid >> 6;
    const int row0 = blockIdx.x * R;
    const unsigned long long lmask_lt = (1ull << lane) - 1ull;

    // init counters + histogram (barrier A below)
    if (tid < R) { ccnt[tid] = 0; mcnt[tid] = 0; scnt[tid] = 0; }
#pragma unroll
    for (int q = 0; q < 4; ++q) ((int*)hist)[q * 256 + tid] = 0;

    // wave-uniform row vectors -> scalar loads (covers init latency)
    float srow[R][B];
#pragma unroll
    for (int r = 0; r < R; ++r)
#pragma unroll
        for (int b = 0; b < B; ++b) srow[r][b] = norm[b * N + row0 + r];

    __syncthreads();   // barrier A: counters/hist zeroed before pushes

    // ---------- pass A: corr + counts + stream-copy W->out + candidate lists ----------
    int cnt_nz[R], cnt_str[R];
#pragma unroll
    for (int r = 0; r < R; ++r) { cnt_nz[r] = 0; cnt_str[r] = 0; }

#pragma unroll
    for (int g = 0; g < 4; ++g) {
        const int j0 = g * 1024 + tid * 4;
        f32x4 w4[R];
#pragma unroll
        for (int r = 0; r < R; ++r)
            w4[r] = __builtin_nontemporal_load((const f32x4*)(W + (size_t)(row0 + r) * N + j0));

        float cc[R][4];
#pragma unroll
        for (int r = 0; r < R; ++r) { cc[r][0] = 0.f; cc[r][1] = 0.f; cc[r][2] = 0.f; cc[r][3] = 0.f; }
#pragma unroll
        for (int half = 0; half < 2; ++half) {
            f32x4 nb[8];
#pragma unroll
            for (int b = 0; b < 8; ++b)
                nb[b] = *(const f32x4*)(norm + (half * 8 + b) * N + j0);
#pragma unroll
            for (int r = 0; r < R; ++r) {
#pragma unroll
                for (int b = 0; b < 8; ++b) {
                    float s = srow[r][half * 8 + b];
                    cc[r][0] = fmaf(s, nb[b][0], cc[r][0]);
                    cc[r][1] = fmaf(s, nb[b][1], cc[r][1]);
                    cc[r][2] = fmaf(s, nb[b][2], cc[r][2]);
                    cc[r][3] = fmaf(s, nb[b][3], cc[r][3]);
                }
            }
        }

        // streaming copy W -> out (fix-ups come later, ordered by barrier B)
#pragma unroll
        for (int r = 0; r < R; ++r)
            *(f32x4*)(out + (size_t)(row0 + r) * N + j0) = w4[r];

#pragma unroll
        for (int r = 0; r < R; ++r) {
            unsigned ev[4];
            bool cf[4], sf[4];
#pragma unroll
            for (int i = 0; i < 4; ++i) {
                float c = cc[r][i] * 0.0625f;       // /16
                float aw = fabsf(w4[r][i]);
                float ac = fabsf(c);
                int isnz = (aw > EPS) ? 1 : 0;
                cnt_nz[r] += isnz;
                cnt_str[r] += (aw >= PRUNE_T) ? 1 : 0;
                cf[i] = (ac > CREATE_T) && (aw < EPS);
                sf[i] = isnz && (aw < PRUNE_T);
                unsigned bits = __float_as_uint(ac);
                unsigned mag = (bits + 0x7FFFu + ((bits >> 16) & 1u)) >> 16;  // RNE bf16
                ev[i] = (mag << 16) | ((c < 0.f) ? 0x8000u : 0u) | (unsigned)(j0 + i);
            }
#pragma unroll
            for (int i = 0; i < 4; ++i) {
                // ballot-aggregated candidate push
                unsigned long long mk = __ballot(cf[i]);
                if (mk) {
                    int ldr = __ffsll(mk) - 1;
                    int pre = __popcll(mk & lmask_lt);
                    int base = 0;
                    if (lane == ldr) base = atomicAdd(&ccnt[r], __popcll(mk));
                    base = __shfl(base, ldr, 64);
                    if (cf[i]) { int idx = base + pre; if (idx < CAPC) cand[r][idx] = ev[i]; }
                }
                // small-weight push (rare, ~0.5/row): direct atomic
                if (sf[i]) {
                    int idx = atomicAdd(&scnt[r], 1);
                    if (idx < CAPS) slist[r][idx] = (unsigned short)(j0 + i);
                }
            }
        }
    }

    // ---------- reduce per-row counters ----------
    int vals[4];
#pragma unroll
    for (int r = 0; r < R; ++r) vals[r] = cnt_nz[r] | (cnt_str[r] << 16);
#pragma unroll
    for (int v = 0; v < 4; ++v) {
        int x = vals[v];
#pragma unroll
        for (int off = 32; off > 0; off >>= 1) x += __shfl_down(x, off, 64);
        if (lane == 0) red[wid][v] = x;
    }
    __syncthreads();   // barrier B: lists, counters, pass-A stores all visible/ordered

    // analytic scalar outputs (no second counting pass)
    int created_total = 0, pruned_total = 0, zeros_total = 0;
#pragma unroll
    for (int r = 0; r < R; ++r) {
        int t = red[0][r] + red[1][r] + red[2][r] + red[3][r];
        int nz = t & 0xFFFF, str = t >> 16;
        int C = ccnt[r];
        int n = 0;
        if (nz < MAX_SYN) { int room = MAX_SYN - nz; n = C < room ? C : room; }
        int strong = str + n;
        int cp = (strong > MIN_SYN) ? 1 : 0;
        created_total += n;
        pruned_total += cp ? (N - strong) : 0;
        zeros_total += (N - nz - n) + (cp ? (nz - str) : 0);
    }
    if (tid == 0) {
        float* slot = acc + (blockIdx.x & (NSLOT - 1)) * 4;
        atomicAdd(slot + 0, (float)created_total);
        atomicAdd(slot + 1, (float)pruned_total);
        atomicAdd(slot + 2, (float)zeros_total);
    }

    // ---------- wave-per-row selection (wave wid owns row wid) ----------
    const int tw = red[0][wid] + red[1][wid] + red[2][wid] + red[3][wid];
    const int nzw = tw & 0xFFFF;
    const int strw = tw >> 16;
    const int Creal = ccnt[wid];
    int nw = 0;
    if (nzw < MAX_SYN) { int room = MAX_SYN - nzw; nw = Creal < room ? Creal : room; }
    const int cpw = ((strw + nw) > MIN_SYN) ? 1 : 0;
    const int Cw = Creal > CAPC ? CAPC : Creal;
    const size_t rowoff = (size_t)(row0 + wid) * N;
    const bool sel = (nw > 0) && (nw < Creal);   // wave-uniform -> barriers below are safe

    if (sel) {
        for (int k0 = 0; k0 < Cw; k0 += 64) {
            int k = k0 + lane;
            if (k < Cw) {
                int bin = (int)(cand[wid][k] >> 16) - (int)BF_BASE;
                if (bin > 255) bin = 255;
                atomicAdd(&hist[wid][bin], 1);
            }
        }
    }
    __syncthreads();   // barrier C: histograms complete

    int mm = 0;
    int cutmag = 0x7FFFFFFF;   // non-sel waves never use it
    if (sel) {
        int h[4], v[4];
#pragma unroll
        for (int q = 0; q < 4; ++q) { h[q] = hist[wid][q * 64 + lane]; v[q] = h[q]; }
#pragma unroll
        for (int off = 1; off < 64; off <<= 1) {
#pragma unroll
            for (int q = 0; q < 4; ++q) {
                int t = __shfl_down(v[q], off, 64);
                v[q] += (lane + off < 64) ? t : 0;
            }
        }
        int T1 = __shfl(v[1], 0, 64);
        int T2 = __shfl(v[2], 0, 64);
        int T3 = __shfl(v[3], 0, 64);
        int suf[4];
        suf[0] = T1 + T2 + T3; suf[1] = T2 + T3; suf[2] = T3; suf[3] = 0;
        int cb = 256;
#pragma unroll
        for (int q = 0; q < 4; ++q) {
            int S = v[q] + suf[q];                      // # entries with bin >= q*64+lane
            if (S >= nw && S - h[q] < nw) { cb = q * 64 + lane; mm = nw - (S - h[q]); }
        }
#pragma unroll
        for (int off = 1; off < 64; off <<= 1) {
            int cb2 = __shfl_xor(cb, off, 64);
            int mm2 = __shfl_xor(mm, off, 64);
            cb = cb < cb2 ? cb : cb2;
            mm = mm > mm2 ? mm : mm2;
        }
        cutmag = cb + (int)BF_BASE;

        // classify: create above-cut, gather boundary ties
        for (int k0 = 0; k0 < Cw; k0 += 64) {
            int k = k0 + lane;
            unsigned e = (k < Cw) ? cand[wid][k] : 0u;
            int mag = (int)(e >> 16);
            bool create = (k < Cw) && (mag > cutmag);
            bool bnd = (k < Cw) && (mag == cutmag);
            unsigned long long mk = __ballot(bnd);
            if (mk) {
                int ldr = __ffsll(mk) - 1;
                int pre = __popcll(mk & lmask_lt);
                int base = 0;
                if (lane == ldr) base = atomicAdd(&mcnt[wid], __popcll(mk));
                base = __shfl(base, ldr, 64);
                if (bnd) { int idx = base + pre; if (idx < CAPM) mlist[wid][idx] = e; }
            }
            if (create)
                out[rowoff + (e & 0xFFFu)] = (e & 0x8000u) ? -INIT_STRENGTH : INIT_STRENGTH;
        }
    }
    __syncthreads();   // barrier D: boundary lists complete

    if (sel) {
        // ties at the cut magnitude: take mm smallest columns (matches prior kernel)
        int L = mcnt[wid]; if (L > CAPM) L = CAPM;
        for (int t0 = 0; t0 < L; t0 += 64) {
            int t = t0 + lane;
            if (t < L) {
                unsigned me = mlist[wid][t];
                int mycol = (int)(me & 0xFFFu);
                int rk = 0;
                for (int t2 = 0; t2 < L; ++t2)
                    rk += ((int)(mlist[wid][t2] & 0xFFFu) < mycol) ? 1 : 0;
                if (rk < mm)
                    out[rowoff + mycol] = (me & 0x8000u) ? -INIT_STRENGTH : INIT_STRENGTH;
            }
        }
    } else if (nw > 0) {
        // n == C: create every stored candidate
        for (int k = lane; k < Cw; k += 64) {
            unsigned e = cand[wid][k];
            out[rowoff + (e & 0xFFFu)] = (e & 0x8000u) ? -INIT_STRENGTH : INIT_STRENGTH;
        }
    }

    // small-weight prune fix-ups (values < PRUNE_T -> 0 when row can prune)
    if (cpw) {
        int S = scnt[wid]; if (S > CAPS) S = CAPS;
        for (int t = lane; t < S; t += 64) out[rowoff + slist[wid][t]] = 0.f;
    }
}

// ---------------- kernel 3: finalize scalars ----------------
__global__ void final_kernel(const float* __restrict__ acc, float* __restrict__ out) {
    float c = 0.f, p = 0.f, z = 0.f;
    for (int s = 0; s < NSLOT; ++s) {
        c += acc[s * 4 + 0];
        p += acc[s * 4 + 1];
        z += acc[s * 4 + 2];
    }
    out[NN + 0] = c;
    out[NN + 1] = p;
    out[NN + 2] = z * (1.0f / (float)NN);
}

extern "C" void kernel_launch(void* const* d_in, const int* in_sizes, int n_in,
                              void* d_out, int out_size, void* d_ws, size_t ws_size,
                              hipStream_t stream) {
    const float* W   = (const float*)d_in[0];   // weight [4096,4096]
    const float* act = (const float*)d_in[1];   // activations [16,4096]
    float* out = (float*)d_out;                 // [w2 (N*N), created, pruned, sparsity]
    float* norm = (float*)d_ws;                 // [B][N] normalized activations
    float* acc = norm + (size_t)B * N;          // 64 slots x 4 float accumulators

    prep_kernel<<<N / 256, 256, 0, stream>>>(act, norm, acc);
    fused_kernel<<<N / R, 256, 0, stream>>>(W, norm, out, acc);
    final_kernel<<<1, 1, 0, stream>>>(acc, out);
}